// Round 19
// baseline (61.398 us; speedup 1.0000x reference)
//
#include <hip/hip_runtime.h>
#include <hip/hip_bf16.h>

// ---------------------------------------------------------------------------
// Fused MLP+LSTM for B=131072 rows, v13: ILP via register double-buffering.
// 512-thread blocks (8 waves, 2 waves/SIMD, ~256 unified regs/wave), M=2
// (32 rows/wave), 256 rows/block, grid = 512. ALL four fat weight layers in
// 144 KB LDS. Each fat layer software-pipelines its LDS weight-frag reads:
// frags for k-step s+1 load into the alternate buffer while step s's MFMAs
// run (fully static unroll). x pair-streamed one step ahead. Tail layers
// (L2..L5) keep the v12-proven serial form.
// Operand-swapped MFMA chain: D = W*act^T keeps batch row at lane&15.
// ---------------------------------------------------------------------------

typedef __bf16 bf16x8 __attribute__((ext_vector_type(8)));
typedef float  f32x4  __attribute__((ext_vector_type(4)));
typedef int    i32x4  __attribute__((ext_vector_type(4)));

#define MFMA16(A, B, C) __builtin_amdgcn_mfma_f32_16x16x32_bf16((A), (B), (C), 0, 0, 0)

// fragment-element offsets (bf16 elems). [0, LDS_ELEMS) staged to LDS.
#define WOFF_FC1    0
#define WOFF_FC1A_H 32768
#define WOFF_FC1B   49152
#define WOFF_FC1C   65536
#define LDS_ELEMS   73728          // 147456 B = 144 KB
#define WOFF_FC1A_W 73728
#define WOFF_FC2    81920
#define WOFF_FC3    83968
#define WOFF_WIH    84992
#define WOFF_WHH    89088
#define WOFF_FC4    93184
#define WTOT        94208
// bias offsets (floats, after bf16 region in ws)
#define BOFF_FC1  0
#define BOFF_FC1A 128
#define BOFF_FC1B 256
#define BOFF_FC1C 384
#define BOFF_FC2  448
#define BOFF_FC3  480
#define BOFF_LSTM 512
#define BOFF_FC4  640
#define BTOT      672

// ---------------------------------------------------------------------------
// Fragment mapping (verified since v1):
//   rel -> j = rel&7, lane = (rel>>3)&63, fs = rel>>9, s = fs%ns, t = fs/ns,
//   gq = lane>>4, n = 16t + (lane&15),
//   k = perm ? 16*(2s + (j>>2)) + 4*gq + (j&3) : 32*s + 8*gq + j
// ---------------------------------------------------------------------------
__device__ __forceinline__ void conv_frag(int rel, const float* __restrict__ src,
                                          __bf16* __restrict__ dst,
                                          int ns, int Krow, int kbase, int klim, int perm) {
    int j    = rel & 7;
    int lane = (rel >> 3) & 63;
    int fs   = rel >> 9;
    int s    = fs % ns;
    int t    = fs / ns;
    int gq   = lane >> 4;
    int n    = 16 * t + (lane & 15);
    int k    = perm ? (16 * (2 * s + (j >> 2)) + 4 * gq + (j & 3))
                    : (32 * s + 8 * gq + j);
    float v  = (k < klim) ? src[n * Krow + kbase + k] : 0.f;
    dst[rel] = (__bf16)v;
}

// ---------------------------------------------------------------------------
// Prep: full fp32 -> bf16 fragment conversion + bias folding (runs once).
// ---------------------------------------------------------------------------
__global__ void prep_kernel(const float* __restrict__ fc1w,  const float* __restrict__ fc1b,
                            const float* __restrict__ fc1aw, const float* __restrict__ fc1ab,
                            const float* __restrict__ fc1bw, const float* __restrict__ fc1bb,
                            const float* __restrict__ wgame, const float* __restrict__ fc1cw,
                            const float* __restrict__ fc1cb, const float* __restrict__ fc2w,
                            const float* __restrict__ fc2b,  const float* __restrict__ fc3w,
                            const float* __restrict__ fc3b,  const float* __restrict__ wih,
                            const float* __restrict__ whh,   const float* __restrict__ bih,
                            const float* __restrict__ bhh,   const float* __restrict__ fc4w,
                            const float* __restrict__ fc4b,
                            __bf16* __restrict__ wsw, float* __restrict__ wsb) {
    int idx = blockIdx.x * 256 + threadIdx.x;
    if (idx < WTOT) {
        if      (idx < WOFF_FC1A_H) conv_frag(idx - WOFF_FC1,    fc1w,  wsw + WOFF_FC1,    8, 256,   0, 256, 0);
        else if (idx < WOFF_FC1B)   conv_frag(idx - WOFF_FC1A_H, fc1aw, wsw + WOFF_FC1A_H, 4, 164,   0, 128, 1);
        else if (idx < WOFF_FC1C)   conv_frag(idx - WOFF_FC1B,   fc1bw, wsw + WOFF_FC1B,   4, 128,   0, 128, 1);
        else if (idx < WOFF_FC1A_W) conv_frag(idx - WOFF_FC1C,   fc1cw, wsw + WOFF_FC1C,   4, 140,   0, 128, 1);
        else if (idx < WOFF_FC2)    conv_frag(idx - WOFF_FC1A_W, fc1aw, wsw + WOFF_FC1A_W, 2, 164, 128,  36, 0);
        else if (idx < WOFF_FC3)    conv_frag(idx - WOFF_FC2,    fc2w,  wsw + WOFF_FC2,    2,  64,   0,  64, 1);
        else if (idx < WOFF_WIH)    conv_frag(idx - WOFF_FC3,    fc3w,  wsw + WOFF_FC3,    1,  32,   0,  32, 1);
        else if (idx < WOFF_WHH)    conv_frag(idx - WOFF_WIH,    wih,   wsw + WOFF_WIH,    1,  32,   0,  32, 1);
        else if (idx < WOFF_FC4)    conv_frag(idx - WOFF_WHH,    whh,   wsw + WOFF_WHH,    1,  32,   0,  32, 0);
        else                        conv_frag(idx - WOFF_FC4,    fc4w,  wsw + WOFF_FC4,    1,  32,   0,  32, 1);
    } else if (idx < WTOT + BTOT) {
        int bi = idx - WTOT;
        float v;
        if      (bi < 128) v = fc1b[bi];
        else if (bi < 256) v = fc1ab[bi - 128];
        else if (bi < 384) v = fc1bb[bi - 256];
        else if (bi < 448) {            // fold fc1c_w[:,128:140] @ w_game into bias
            int n = bi - 384;
            v = fc1cb[n];
            for (int q = 0; q < 12; ++q) v += fc1cw[n * 140 + 128 + q] * wgame[q];
        }
        else if (bi < 480) v = fc2b[bi - 448];
        else if (bi < 512) v = fc3b[bi - 480];
        else if (bi < 640) { int n = bi - 512; v = bih[n] + bhh[n]; }   // fused LSTM bias
        else               v = fc4b[bi - 640];
        wsb[bi] = v;
    }
}

// ---------------------------------------------------------------------------
// Helpers
// ---------------------------------------------------------------------------
__device__ __forceinline__ bf16x8 ld8f(const float* __restrict__ p) {
    f32x4 a = *(const f32x4*)p;
    f32x4 b = *(const f32x4*)(p + 4);
    bf16x8 r;
    r[0] = (__bf16)a[0]; r[1] = (__bf16)a[1]; r[2] = (__bf16)a[2]; r[3] = (__bf16)a[3];
    r[4] = (__bf16)b[0]; r[5] = (__bf16)b[1]; r[6] = (__bf16)b[2]; r[7] = (__bf16)b[3];
    return r;
}

__device__ __forceinline__ bf16x8 ld4f_masked(const float* __restrict__ p, bool on) {
    f32x4 v = {0.f, 0.f, 0.f, 0.f};
    if (on) v = *(const f32x4*)p;
    bf16x8 r;
    r[0] = (__bf16)v[0]; r[1] = (__bf16)v[1]; r[2] = (__bf16)v[2]; r[3] = (__bf16)v[3];
    r[4] = (__bf16)0.f;  r[5] = (__bf16)0.f;  r[6] = (__bf16)0.f;  r[7] = (__bf16)0.f;
    return r;
}

// pack acc[2s],acc[2s+1] (n = 16t+4g+r) into next-layer B-frag, with relu
__device__ __forceinline__ bf16x8 packrelu(const f32x4* a, int s) {
    bf16x8 r;
#pragma unroll
    for (int j = 0; j < 8; ++j) {
        float v = a[2 * s + (j >> 2)][j & 3];
        r[j] = (__bf16)fmaxf(v, 0.f);
    }
    return r;
}

__device__ __forceinline__ float sigm(float v)  { return 1.f / (1.f + __expf(-v)); }
__device__ __forceinline__ float tanh_(float v) { return 1.f - 2.f / (1.f + __expf(2.f * v)); }

// ---------------------------------------------------------------------------
// Fused main kernel: 8 waves/block, 32 rows/wave (M=2), 256 rows/block
// ---------------------------------------------------------------------------
__global__ __launch_bounds__(512, 2) void fused_mlp_lstm(
        const float* __restrict__ x,  const float* __restrict__ w,
        const float* __restrict__ h0, const float* __restrict__ c0,
        const float* __restrict__ fc5w, const float* __restrict__ fc5b,
        const __bf16* __restrict__ wsw, const float* __restrict__ wsb,
        float* __restrict__ out) {
    __shared__ __align__(16) __bf16 slds[LDS_ELEMS];   // 144 KB

    const int tid     = threadIdx.x;
    const int lane    = tid & 63;
    const int wv      = tid >> 6;
    const int gq      = lane >> 4;
    const int mr      = lane & 15;
    const int rowbase = blockIdx.x * 256 + wv * 32;
    const int rowA    = rowbase + mr;
    const int rowB    = rowA + 16;

    // ---- stage all big weight layers to LDS (18 x 16B per thread) ---------
    {
        const i32x4* gs = (const i32x4*)wsw;
        i32x4*       sd = (i32x4*)slds;
#pragma unroll
        for (int i = 0; i < 18; ++i) sd[i * 512 + tid] = gs[i * 512 + tid];
    }
    __syncthreads();

    const bf16x8* Wfc1  = (const bf16x8*)(slds + WOFF_FC1);
    const bf16x8* Wf1aH = (const bf16x8*)(slds + WOFF_FC1A_H);
    const bf16x8* Wfc1b = (const bf16x8*)(slds + WOFF_FC1B);
    const bf16x8* Wfc1c = (const bf16x8*)(slds + WOFF_FC1C);
    const bf16x8* Wf1aW = (const bf16x8*)(wsw + WOFF_FC1A_W);
    const bf16x8* Wfc2  = (const bf16x8*)(wsw + WOFF_FC2);
    const bf16x8* Wfc3  = (const bf16x8*)(wsw + WOFF_FC3);
    const bf16x8* Wwih  = (const bf16x8*)(wsw + WOFF_WIH);
    const bf16x8* Wwhh  = (const bf16x8*)(wsw + WOFF_WHH);
    const bf16x8* Wfc4  = (const bf16x8*)(wsw + WOFF_FC4);

    bf16x8 fb[2][8];   // double-buffered weight frags (static-indexed only)

    // ---- L1: x[256] -> h1[128]  (frag+x double-buffered) ------------------
    bf16x8 h1fA[4], h1fB[4];
    {
        f32x4 aA[8], aB[8];
#pragma unroll
        for (int t = 0; t < 8; ++t) {
            f32x4 bv = *(const f32x4*)(wsb + BOFF_FC1 + 16 * t + 4 * gq);
            aA[t] = bv; aB[t] = bv;
        }
        const float* xrA = x + rowA * 256 + 8 * gq;
        const float* xrB = x + rowB * 256 + 8 * gq;
        bf16x8 xa = ld8f(xrA);
        bf16x8 xb = ld8f(xrB);
#pragma unroll
        for (int t = 0; t < 8; ++t) fb[0][t] = Wfc1[(t * 8 + 0) * 64 + lane];
#pragma unroll
        for (int s = 0; s < 8; ++s) {
            const int cur = s & 1, nxt = cur ^ 1;
            bf16x8 xa_n = xa, xb_n = xb;
            if (s < 7) {
                xa_n = ld8f(xrA + 32 * (s + 1));
                xb_n = ld8f(xrB + 32 * (s + 1));
#pragma unroll
                for (int t = 0; t < 8; ++t) fb[nxt][t] = Wfc1[(t * 8 + s + 1) * 64 + lane];
            }
#pragma unroll
            for (int t = 0; t < 8; ++t) {
                aA[t] = MFMA16(fb[cur][t], xa, aA[t]);
                aB[t] = MFMA16(fb[cur][t], xb, aB[t]);
            }
            xa = xa_n; xb = xb_n;
        }
#pragma unroll
        for (int s = 0; s < 4; ++s) { h1fA[s] = packrelu(aA, s); h1fB[s] = packrelu(aB, s); }
    }

    // ---- L1a: [h1, w] (128+36) -> h2[128]  (6 k-steps: 4 LDS + 2 global) --
    bf16x8 h2fA[4], h2fB[4];
    {
        bf16x8 wxa0 = ld8f(w + rowA * 36 + 8 * gq);
        bf16x8 wxb0 = ld8f(w + rowB * 36 + 8 * gq);
        bf16x8 wxa1 = ld4f_masked(w + rowA * 36 + 32, gq == 0);
        bf16x8 wxb1 = ld4f_masked(w + rowB * 36 + 32, gq == 0);
        f32x4 aA[8], aB[8];
#pragma unroll
        for (int t = 0; t < 8; ++t) {
            f32x4 bv = *(const f32x4*)(wsb + BOFF_FC1A + 16 * t + 4 * gq);
            aA[t] = bv; aB[t] = bv;
        }
#pragma unroll
        for (int t = 0; t < 8; ++t) fb[0][t] = Wf1aH[(t * 4 + 0) * 64 + lane];
#pragma unroll
        for (int s = 0; s < 6; ++s) {
            const int cur = s & 1, nxt = cur ^ 1;
            if (s < 3) {
#pragma unroll
                for (int t = 0; t < 8; ++t) fb[nxt][t] = Wf1aH[(t * 4 + s + 1) * 64 + lane];
            } else if (s < 5) {
#pragma unroll
                for (int t = 0; t < 8; ++t) fb[nxt][t] = Wf1aW[(t * 2 + (s - 3)) * 64 + lane];
            }
            bf16x8 actA = (s < 4) ? h1fA[s < 4 ? s : 0] : (s == 4 ? wxa0 : wxa1);
            bf16x8 actB = (s < 4) ? h1fB[s < 4 ? s : 0] : (s == 4 ? wxb0 : wxb1);
#pragma unroll
            for (int t = 0; t < 8; ++t) {
                aA[t] = MFMA16(fb[cur][t], actA, aA[t]);
                aB[t] = MFMA16(fb[cur][t], actB, aB[t]);
            }
        }
#pragma unroll
        for (int s = 0; s < 4; ++s) { h2fA[s] = packrelu(aA, s); h2fB[s] = packrelu(aB, s); }
    }

    // ---- L1b: h2[128] -> h3[128]  (4 k-steps, double-buffered) ------------
    bf16x8 h3fA[4], h3fB[4];
    {
        f32x4 aA[8], aB[8];
#pragma unroll
        for (int t = 0; t < 8; ++t) {
            f32x4 bv = *(const f32x4*)(wsb + BOFF_FC1B + 16 * t + 4 * gq);
            aA[t] = bv; aB[t] = bv;
        }
#pragma unroll
        for (int t = 0; t < 8; ++t) fb[0][t] = Wfc1b[(t * 4 + 0) * 64 + lane];
#pragma unroll
        for (int s = 0; s < 4; ++s) {
            const int cur = s & 1, nxt = cur ^ 1;
            if (s < 3) {
#pragma unroll
                for (int t = 0; t < 8; ++t) fb[nxt][t] = Wfc1b[(t * 4 + s + 1) * 64 + lane];
            }
#pragma unroll
            for (int t = 0; t < 8; ++t) {
                aA[t] = MFMA16(fb[cur][t], h2fA[s], aA[t]);
                aB[t] = MFMA16(fb[cur][t], h2fB[s], aB[t]);
            }
        }
#pragma unroll
        for (int s = 0; s < 4; ++s) { h3fA[s] = packrelu(aA, s); h3fB[s] = packrelu(aB, s); }
    }

    // LSTM-state inputs: needed 2 layers from here; issue now
    bf16x8 h0fA = ld8f(h0 + rowA * 32 + 8 * gq);
    bf16x8 h0fB = ld8f(h0 + rowB * 32 + 8 * gq);
    f32x4  cA0 = *(const f32x4*)(c0 + rowA * 32 + 4 * gq);
    f32x4  cA1 = *(const f32x4*)(c0 + rowA * 32 + 16 + 4 * gq);
    f32x4  cB0 = *(const f32x4*)(c0 + rowB * 32 + 4 * gq);
    f32x4  cB1 = *(const f32x4*)(c0 + rowB * 32 + 16 + 4 * gq);

    // ---- L1c: [h3] -> h4[64]  (4 k-steps, t=4, double-buffered) -----------
    bf16x8 h4fA[2], h4fB[2];
    {
        f32x4 aA[4], aB[4];
#pragma unroll
        for (int t = 0; t < 4; ++t) {
            f32x4 bv = *(const f32x4*)(wsb + BOFF_FC1C + 16 * t + 4 * gq);
            aA[t] = bv; aB[t] = bv;
        }
#pragma unroll
        for (int t = 0; t < 4; ++t) fb[0][t] = Wfc1c[(t * 4 + 0) * 64 + lane];
#pragma unroll
        for (int s = 0; s < 4; ++s) {
            const int cur = s & 1, nxt = cur ^ 1;
            if (s < 3) {
#pragma unroll
                for (int t = 0; t < 4; ++t) fb[nxt][t] = Wfc1c[(t * 4 + s + 1) * 64 + lane];
            }
#pragma unroll
            for (int t = 0; t < 4; ++t) {
                aA[t] = MFMA16(fb[cur][t], h3fA[s], aA[t]);
                aB[t] = MFMA16(fb[cur][t], h3fB[s], aB[t]);
            }
        }
#pragma unroll
        for (int s = 0; s < 2; ++s) { h4fA[s] = packrelu(aA, s); h4fB[s] = packrelu(aB, s); }
    }

    // ---- L2: h4[64] -> h5[32] --------------------------------------------
    bf16x8 h5fA, h5fB;
    {
        f32x4 aA[2], aB[2];
#pragma unroll
        for (int t = 0; t < 2; ++t) {
            f32x4 bv = *(const f32x4*)(wsb + BOFF_FC2 + 16 * t + 4 * gq);
            aA[t] = bv; aB[t] = bv;
        }
#pragma unroll
        for (int s = 0; s < 2; ++s)
#pragma unroll
            for (int t = 0; t < 2; ++t) {
                bf16x8 wf = Wfc2[(t * 2 + s) * 64 + lane];
                aA[t] = MFMA16(wf, h4fA[s], aA[t]);
                aB[t] = MFMA16(wf, h4fB[s], aB[t]);
            }
        h5fA = packrelu(aA, 0); h5fB = packrelu(aB, 0);
    }

    // ---- L3: h5[32] -> h6[32] --------------------------------------------
    bf16x8 h6fA, h6fB;
    {
        f32x4 aA[2], aB[2];
#pragma unroll
        for (int t = 0; t < 2; ++t) {
            f32x4 bv = *(const f32x4*)(wsb + BOFF_FC3 + 16 * t + 4 * gq);
            aA[t] = bv; aB[t] = bv;
        }
#pragma unroll
        for (int t = 0; t < 2; ++t) {
            bf16x8 wf = Wfc3[t * 64 + lane];
            aA[t] = MFMA16(wf, h5fA, aA[t]);
            aB[t] = MFMA16(wf, h5fB, aB[t]);
        }
        h6fA = packrelu(aA, 0); h6fB = packrelu(aB, 0);
    }

    // ---- LSTM gates ------------------------------------------------------
    bf16x8 hnfA, hnfB;
    {
        f32x4 gA[8], gB[8];
#pragma unroll
        for (int t = 0; t < 8; ++t) {
            f32x4 bv = *(const f32x4*)(wsb + BOFF_LSTM + 16 * t + 4 * gq);
            gA[t] = bv; gB[t] = bv;
        }
#pragma unroll
        for (int t = 0; t < 8; ++t) {
            bf16x8 wf = Wwih[t * 64 + lane];
            gA[t] = MFMA16(wf, h6fA, gA[t]);
            gB[t] = MFMA16(wf, h6fB, gB[t]);
        }
#pragma unroll
        for (int t = 0; t < 8; ++t) {
            bf16x8 wf = Wwhh[t * 64 + lane];
            gA[t] = MFMA16(wf, h0fA, gA[t]);
            gB[t] = MFMA16(wf, h0fB, gB[t]);
        }
        // gate tiles: i -> {0,1}, f -> {2,3}, g -> {4,5}, o -> {6,7}
#pragma unroll
        for (int t2 = 0; t2 < 2; ++t2) {
            f32x4 ccA = t2 ? cA1 : cA0;
            f32x4 ccB = t2 ? cB1 : cB0;
#pragma unroll
            for (int r = 0; r < 4; ++r) {
                float cnA = sigm(gA[2 + t2][r]) * ccA[r] + sigm(gA[t2][r]) * tanh_(gA[4 + t2][r]);
                float cnB = sigm(gB[2 + t2][r]) * ccB[r] + sigm(gB[t2][r]) * tanh_(gB[4 + t2][r]);
                hnfA[t2 * 4 + r] = (__bf16)(sigm(gA[6 + t2][r]) * tanh_(cnA));
                hnfB[t2 * 4 + r] = (__bf16)(sigm(gB[6 + t2][r]) * tanh_(cnB));
            }
        }
    }

    // ---- L4: h_new[32] -> o1[32] -----------------------------------------
    f32x4 oA[2], oB[2];
#pragma unroll
    for (int t = 0; t < 2; ++t) {
        f32x4 bv = *(const f32x4*)(wsb + BOFF_FC4 + 16 * t + 4 * gq);
        oA[t] = bv; oB[t] = bv;
    }
#pragma unroll
    for (int t = 0; t < 2; ++t) {
        bf16x8 wf = Wfc4[t * 64 + lane];
        oA[t] = MFMA16(wf, hnfA, oA[t]);
        oB[t] = MFMA16(wf, hnfB, oB[t]);
    }

    // ---- L5 + sigmoid ----------------------------------------------------
    f32x4 w5a = *(const f32x4*)(fc5w + 4 * gq);
    f32x4 w5b = *(const f32x4*)(fc5w + 16 + 4 * gq);
    float b5  = fc5b[0];
    float pA = 0.f, pB = 0.f;
#pragma unroll
    for (int r = 0; r < 4; ++r) {
        pA += fmaxf(oA[0][r], 0.f) * w5a[r];
        pA += fmaxf(oA[1][r], 0.f) * w5b[r];
        pB += fmaxf(oB[0][r], 0.f) * w5a[r];
        pB += fmaxf(oB[1][r], 0.f) * w5b[r];
    }
    pA += __shfl_xor(pA, 16); pA += __shfl_xor(pA, 32);
    pB += __shfl_xor(pB, 16); pB += __shfl_xor(pB, 32);
    float resA = sigm(pA + b5);
    float resB = sigm(pB + b5);
    if (lane < 16) {
        out[rowbase + lane]      = resA;
        out[rowbase + 16 + lane] = resB;
    }
}

// ---------------------------------------------------------------------------
extern "C" void kernel_launch(void* const* d_in, const int* in_sizes, int n_in,
                              void* d_out, int out_size, void* d_ws, size_t ws_size,
                              hipStream_t stream) {
    const float* x     = (const float*)d_in[0];
    const float* w     = (const float*)d_in[1];
    const float* h0    = (const float*)d_in[2];
    const float* c0    = (const float*)d_in[3];
    const float* fc1w  = (const float*)d_in[4];
    const float* fc1b  = (const float*)d_in[5];
    const float* fc1aw = (const float*)d_in[6];
    const float* fc1ab = (const float*)d_in[7];
    const float* fc1bw = (const float*)d_in[8];
    const float* fc1bb = (const float*)d_in[9];
    const float* wgame = (const float*)d_in[10];
    const float* fc1cw = (const float*)d_in[11];
    const float* fc1cb = (const float*)d_in[12];
    const float* fc2w  = (const float*)d_in[13];
    const float* fc2b  = (const float*)d_in[14];
    const float* fc3w  = (const float*)d_in[15];
    const float* fc3b  = (const float*)d_in[16];
    const float* wih   = (const float*)d_in[17];
    const float* whh   = (const float*)d_in[18];
    const float* bih   = (const float*)d_in[19];
    const float* bhh   = (const float*)d_in[20];
    const float* fc4w  = (const float*)d_in[21];
    const float* fc4b  = (const float*)d_in[22];
    const float* fc5w  = (const float*)d_in[23];
    const float* fc5b  = (const float*)d_in[24];

    __bf16* wsw = (__bf16*)d_ws;
    float*  wsb = (float*)((char*)d_ws + WTOT * sizeof(__bf16));
    (void)ws_size; (void)n_in; (void)out_size;

    const int Btot = in_sizes[0] / 256;   // 131072 rows

    prep_kernel<<<(WTOT + BTOT + 255) / 256, 256, 0, stream>>>(
        fc1w, fc1b, fc1aw, fc1ab, fc1bw, fc1bb, wgame, fc1cw, fc1cb,
        fc2w, fc2b, fc3w, fc3b, wih, whh, bih, bhh, fc4w, fc4b, wsw, wsb);

    fused_mlp_lstm<<<Btot / 256, 512, 0, stream>>>(
        x, w, h0, c0, fc5w, fc5b, wsw, wsb, (float*)d_out);
}